// Round 6
// baseline (54.220 us; speedup 1.0000x reference)
//
#include <hip/hip_runtime.h>
#include <math.h>

#define NB 16
#define BQ 2048
#define NC 256
#define NL 255   // labels 0..254 (class 255 excluded)

typedef unsigned long long u64;
typedef unsigned int u32;
typedef unsigned short u16;
typedef unsigned char u8;

__device__ __forceinline__ u32 ord_f32(float f) {
  u32 b = __float_as_uint(f);
  return (b & 0x80000000u) ? ~b : (b | 0x80000000u);
}

// Kernel A: 16 lanes per query (4 queries per wave). PROVEN absmax=0 in r5 —
// arithmetic and reduction DAG must not change.
__global__ __launch_bounds__(256) void score_box_kernel(
    const float* __restrict__ logits,
    const float* __restrict__ pboxes,
    const int* __restrict__ tsz,
    float* __restrict__ out)
{
#pragma clang fp contract(off)
  const int lane = threadIdx.x & 63;
  const int g = lane & 15;            // sub-lane within the 16-lane group
  const int wv = threadIdx.x >> 6;
  const int q = (blockIdx.x * 4 + wv) * 4 + (lane >> 4);  // 16 queries/block
  const float* row = logits + (size_t)q * NC + g * 16;
  const float4 la = *reinterpret_cast<const float4*>(row);
  const float4 lb4 = *reinterpret_cast<const float4*>(row + 4);
  const float4 lc = *reinterpret_cast<const float4*>(row + 8);
  const float4 ld = *reinterpret_cast<const float4*>(row + 12);

  float m = fmaxf(fmaxf(fmaxf(la.x, la.y), fmaxf(la.z, la.w)),
           fmaxf(fmaxf(fmaxf(lb4.x, lb4.y), fmaxf(lb4.z, lb4.w)),
           fmaxf(fmaxf(fmaxf(lc.x, lc.y), fmaxf(lc.z, lc.w)),
                 fmaxf(fmaxf(ld.x, ld.y), fmaxf(ld.z, ld.w)))));
  #pragma unroll
  for (int d = 1; d < 16; d <<= 1) m = fmaxf(m, __shfl_xor(m, d));

  float4 ea, eb, ec, ed;
  ea.x = expf(la.x - m);  ea.y = expf(la.y - m);  ea.z = expf(la.z - m);  ea.w = expf(la.w - m);
  eb.x = expf(lb4.x - m); eb.y = expf(lb4.y - m); eb.z = expf(lb4.z - m); eb.w = expf(lb4.w - m);
  ec.x = expf(lc.x - m);  ec.y = expf(lc.y - m);  ec.z = expf(lc.z - m);  ec.w = expf(lc.w - m);
  ed.x = expf(ld.x - m);  ed.y = expf(ld.y - m);  ed.z = expf(ld.z - m);  ed.w = expf(ld.w - m);

  float s = (((ea.x + ea.y) + (ea.z + ea.w)) + ((eb.x + eb.y) + (eb.z + eb.w)))
          + (((ec.x + ec.y) + (ec.z + ec.w)) + ((ed.x + ed.y) + (ed.z + ed.w)));
  #pragma unroll
  for (int d = 1; d < 16; d <<= 1) s += __shfl_xor(s, d);

  const int c0 = g * 16;
  float bp = ea.x / s; int bc = c0;
  float p;
  p = ea.y / s; if (p > bp) { bp = p; bc = c0 + 1; }
  p = ea.z / s; if (p > bp) { bp = p; bc = c0 + 2; }
  p = ea.w / s; if (p > bp) { bp = p; bc = c0 + 3; }
  p = eb.x / s; if (p > bp) { bp = p; bc = c0 + 4; }
  p = eb.y / s; if (p > bp) { bp = p; bc = c0 + 5; }
  p = eb.z / s; if (p > bp) { bp = p; bc = c0 + 6; }
  p = eb.w / s; if (p > bp) { bp = p; bc = c0 + 7; }
  p = ec.x / s; if (p > bp) { bp = p; bc = c0 + 8; }
  p = ec.y / s; if (p > bp) { bp = p; bc = c0 + 9; }
  p = ec.z / s; if (p > bp) { bp = p; bc = c0 + 10; }
  p = ec.w / s; if (p > bp) { bp = p; bc = c0 + 11; }
  p = ed.x / s; if (p > bp) { bp = p; bc = c0 + 12; }
  p = ed.y / s; if (p > bp) { bp = p; bc = c0 + 13; }
  p = ed.z / s; if (p > bp) { bp = p; bc = c0 + 14; }
  p = ed.w / s; if (g != 15 && p > bp) { bp = p; bc = c0 + 15; }  // skip class 255
  #pragma unroll
  for (int d = 1; d < 16; d <<= 1) {
    const float op = __shfl_xor(bp, d);
    const int   oc = __shfl_xor(bc, d);
    if (op > bp || (op == bp && oc < bc)) { bp = op; bc = oc; }
  }

  if (g == 0) {
    const int b = q >> 11;
    float hf = (float)tsz[b * 2 + 0];
    float wf = (float)tsz[b * 2 + 1];
    float4 pb = *reinterpret_cast<const float4*>(pboxes + (size_t)q * 4);
    float hw = 0.5f * pb.z, hh = 0.5f * pb.w;
    float4 ob;
    ob.x = (pb.x - hw) * wf;
    ob.y = (pb.y - hh) * hf;
    ob.z = (pb.x + hw) * wf;
    ob.w = (pb.y + hh) * hf;
    *reinterpret_cast<float4*>(out + (size_t)q * 4) = ob;
    out[NB * BQ * 4 + q] = bp;
    out[NB * BQ * 5 + q] = (float)bc;
  }
}

// Kernel B: one 1024-thread block per batch. RANK (counting) sort replaces
// bitonic: key = (ord(score)<<32)|(idx<<8)|label (label bits BELOW idx ->
// ordering identical to the proven (ord,idx) key). One counting pass yields
// sorted position (#greater), label-rank g (#greater same-label), and label
// offset (#smaller-label), eliminating hist/scan/scatter phases. 5 barriers.
__global__ __launch_bounds__(1024) void sort_nms_kernel(float* __restrict__ out)
{
#pragma clang fp contract(off)
  __shared__ __align__(16) u64 key[BQ];   // sorted keys + invalid tail
  __shared__ __align__(16) u64 ovlg[BQ];  // phase1-2: compact valid keys; phase3+: suppression masks
  __shared__ float4 bx[BQ];               // boxes by orig idx
  __shared__ float4 bxo[BQ];              // label-offset coords by sorted position
  __shared__ float sc[BQ];                // raw scores by orig idx
  __shared__ u8 lb[BQ];                   // labels by orig idx
  __shared__ u8 kp[BQ];                   // keep flags by sorted position
  __shared__ u16 gof[BQ];                 // label-rank g by sorted position
  __shared__ u16 gpos[BQ];                // sorted position by group slot
  __shared__ u32 offl[256];               // group start by label (benign same-value race)
  __shared__ u32 kcnt[256];               // per-label member count
  __shared__ u32 wval[16], winv[16];      // per-wave valid/invalid counts

  const int b = blockIdx.x;
  const int tid = threadIdx.x;
  const int lane = tid & 63;
  const int wv = tid >> 6;
  float* boxes_g  = out + (size_t)b * BQ * 4;
  float* scores_g = out + NB * BQ * 4 + (size_t)b * BQ;
  float* labels_g = out + NB * BQ * 5 + (size_t)b * BQ;
  float* keep_g   = out + NB * BQ * 6 + (size_t)b * BQ;

  // ---- phase 1: load, stage, compaction ranks ----
  const int q0 = 2 * tid;
  float2 s2 = *reinterpret_cast<const float2*>(scores_g + q0);
  float2 lf = *reinterpret_cast<const float2*>(labels_g + q0);
  float4 bb0 = *reinterpret_cast<const float4*>(boxes_g + (size_t)q0 * 4);
  float4 bb1 = *reinterpret_cast<const float4*>(boxes_g + (size_t)q0 * 4 + 4);
  sc[q0] = s2.x; sc[q0 + 1] = s2.y;
  const u32 l0 = (u32)(int)lf.x, l1 = (u32)(int)lf.y;
  lb[q0] = (u8)l0; lb[q0 + 1] = (u8)l1;
  bx[q0] = bb0; bx[q0 + 1] = bb1;
  const bool v0 = (s2.x >= 0.05f), v1 = (s2.y >= 0.05f);
  // key: (ord<<32)|(idx<<8)|label — label never decides order (idx unique)
  const u64 f0 = ((u64)(v0 ? ord_f32(s2.x) : 0x007FFFFFu) << 32) | ((u32)q0 << 8) | l0;
  const u64 f1 = ((u64)(v1 ? ord_f32(s2.y) : 0x007FFFFFu) << 32) | ((u32)(q0 + 1) << 8) | l1;
  const u64 b0 = __ballot(v0), b1 = __ballot(v1);
  if (lane == 0) {
    const u32 c = (u32)(__popcll(b0) + __popcll(b1));
    wval[wv] = c;
    winv[wv] = 128u - c;
  }
  if (tid < 256) kcnt[tid] = 0;
  __syncthreads();  // B0: wval/winv ready

  int nv = 0, voff = 0, ioff = 0;
  #pragma unroll
  for (int w = 0; w < 16; ++w) {
    const int c = (int)wval[w];
    nv += c;
    if (w < wv) { voff += c; ioff += (int)winv[w]; }
  }
  const int tinv = BQ - nv;
  const u64 below = (1ull << lane) - 1ull;
  const int vr0 = voff + (int)__popcll(b0 & below) + (int)__popcll(b1 & below);
  const int ir0 = ioff + (int)__popcll(~b0 & below) + (int)__popcll(~b1 & below);
  const int vr1 = vr0 + (v0 ? 1 : 0);
  const int ir1 = ir0 + (v0 ? 0 : 1);
  // invalid tail position nv + (tinv-1-ir) = descending original index (EXACT
  // reversed-stable semantics for the -inf block) — proven in r3-r5.
  if (v0) ovlg[vr0] = f0; else { const int ip = nv + (tinv - 1 - ir0); key[ip] = f0; kp[ip] = 0; }
  if (v1) ovlg[vr1] = f1; else { const int ip = nv + (tinv - 1 - ir1); key[ip] = f1; kp[ip] = 0; }
  __syncthreads();  // B1: compact valid keys + invalid tail staged

  // ---- phase 2: rank pass (counting sort + label grouping in one pass) ----
  if (nv > 0) {
    u32 S = 1; int logS = 0;
    while ((int)S < nv) { S <<= 1; ++logS; }
    int tshift = 10 - logS; if (tshift < 0) tshift = 0; if (tshift > 6) tshift = 6;
    const int tps = 1 << tshift;             // threads cooperating per slot
    const int qtr = tid & (tps - 1);
    const int sstep = 1024 >> tshift;        // slots covered per sweep
    for (int slot = tid >> tshift; slot < nv; slot += sstep) {
      const u64 ki = ovlg[slot];
      const u32 li = (u32)ki & 255u;
      const int jlo = (nv * qtr) >> tshift;
      const int jhi = (nv * (qtr + 1)) >> tshift;
      int cgt = 0, lgt = 0, llt = 0;
      for (int j = jlo; j < jhi; ++j) {
        const u64 kj = ovlg[j];
        const u32 lj = (u32)kj & 255u;
        cgt += (kj > ki) ? 1 : 0;
        lgt += ((kj > ki) & (lj == li)) ? 1 : 0;
        llt += (lj < li) ? 1 : 0;
      }
      #pragma unroll
      for (int d = 1; d < 64; d <<= 1) {
        if (d >= tps) break;
        cgt += __shfl_xor(cgt, d);
        lgt += __shfl_xor(lgt, d);
        llt += __shfl_xor(llt, d);
      }
      if (qtr == 0) {
        const int p = cgt;                   // sorted position (descending)
        key[p] = ki;
        gof[p] = (u16)lgt;
        gpos[llt + lgt] = (u16)p;
        offl[li] = (u32)llt;                 // same value for all of label li
        atomicAdd(&kcnt[li], 1u);
        const u32 oi = (u32)(ki >> 8) & (BQ - 1);
        const float lc = (float)li * 100000.0f;
        const float4 A = bx[oi];
        float4 Ao;
        Ao.x = A.x + lc; Ao.y = A.y + lc; Ao.z = A.z + lc; Ao.w = A.w + lc;
        bxo[p] = Ao;                         // exact same ops as inline offset
      }
    }
  }
  __syncthreads();  // B2: sorted keys, groups, offset coords ready

  // ---- phase 3: parallel overlap-mask build (one thread per valid element) ----
  #pragma unroll
  for (int half = 0; half < 2; ++half) {
    const int p = tid + half * 1024;
    if (p < nv) {
      const u32 li = (u32)key[p] & 255u;
      const u32 g = gof[p];
      if (g < 64) {
        const u32 st = offl[li];
        const float4 Ao = bxo[p];
        const float areaA = fmaxf(Ao.z - Ao.x, 0.0f) * fmaxf(Ao.w - Ao.y, 0.0f);
        u64 m = 0;
        for (u32 r = 0; r < g; ++r) {
          const int p2 = gpos[st + r];
          const float4 Bo = bxo[p2];
          const float areaB = fmaxf(Bo.z - Bo.x, 0.0f) * fmaxf(Bo.w - Bo.y, 0.0f);
          const float ltx = fmaxf(Ao.x, Bo.x), lty = fmaxf(Ao.y, Bo.y);
          const float rbx = fminf(Ao.z, Bo.z), rby = fminf(Ao.w, Bo.w);
          const float iw = fmaxf(rbx - ltx, 0.0f), ih = fmaxf(rby - lty, 0.0f);
          const float inter = iw * ih;
          const float uni = (areaA + areaB) - inter;
          const float iou = inter / fmaxf(uni, 1e-6f);
          if (iou > 0.7f) m |= (1ull << r);
        }
        ovlg[st + g] = m;   // safe: compact-key reads finished at B2
      }
    }
  }
  __syncthreads();  // B3

  // ---- phase 4: per-label greedy resolution (bitops; serial fallback k>64) ----
  if (tid < NL) {
    const int k = (int)kcnt[tid];
    if (k > 0) {
      const int st = (int)offl[tid];
      if (k <= 64) {
        u64 kept = 0;
        for (int r = 0; r < k; ++r) {
          const u64 m = ovlg[st + r];
          const int keep = ((m & kept) == 0) ? 1 : 0;
          kept |= (u64)keep << r;
          kp[gpos[st + r]] = (u8)keep;
        }
      } else {
        for (int a = 0; a < k; ++a) {
          const int p = gpos[st + a];
          const float4 Ao = bxo[p];
          const float areaA = fmaxf(Ao.z - Ao.x, 0.0f) * fmaxf(Ao.w - Ao.y, 0.0f);
          int keep = 1;
          for (int e = 0; e < a; ++e) {
            const int p2 = gpos[st + e];
            if (!kp[p2]) continue;
            const float4 Bo = bxo[p2];
            const float areaB = fmaxf(Bo.z - Bo.x, 0.0f) * fmaxf(Bo.w - Bo.y, 0.0f);
            const float ltx = fmaxf(Ao.x, Bo.x), lty = fmaxf(Ao.y, Bo.y);
            const float rbx = fminf(Ao.z, Bo.z), rby = fminf(Ao.w, Bo.w);
            const float iw = fmaxf(rbx - ltx, 0.0f), ih = fmaxf(rby - lty, 0.0f);
            const float inter = iw * ih;
            const float uni = (areaA + areaB) - inter;
            const float iou = inter / fmaxf(uni, 1e-6f);
            if (iou > 0.7f) { keep = 0; break; }
          }
          kp[p] = (u8)keep;
        }
      }
    }
  }
  __syncthreads();  // B4

  // ---- phase 5: writeback sorted outputs ----
  {
    const int p = tid;
    const u32 oi = (u32)(key[p] >> 8) & (BQ - 1);
    *reinterpret_cast<float4*>(boxes_g + (size_t)p * 4) = bx[oi];
    scores_g[p] = sc[oi];
    labels_g[p] = (float)lb[oi];
    keep_g[p]   = kp[p] ? 1.0f : 0.0f;
  }
  {
    const int p = tid + 1024;
    const u32 oi = (u32)(key[p] >> 8) & (BQ - 1);
    *reinterpret_cast<float4*>(boxes_g + (size_t)p * 4) = bx[oi];
    scores_g[p] = sc[oi];
    labels_g[p] = (float)lb[oi];
    keep_g[p]   = kp[p] ? 1.0f : 0.0f;
  }
}

extern "C" void kernel_launch(void* const* d_in, const int* in_sizes, int n_in,
                              void* d_out, int out_size, void* d_ws, size_t ws_size,
                              hipStream_t stream) {
  const float* logits = (const float*)d_in[0];
  const float* pboxes = (const float*)d_in[1];
  const int*   tsz    = (const int*)d_in[2];
  float* out = (float*)d_out;
  score_box_kernel<<<NB * BQ / 16, 256, 0, stream>>>(logits, pboxes, tsz, out);
  sort_nms_kernel<<<NB, 1024, 0, stream>>>(out);
}

// Round 7
// 29.996 us; speedup vs baseline: 1.8076x; 1.8076x over previous
//
#include <hip/hip_runtime.h>
#include <math.h>

#define NB 16
#define BQ 2048
#define NC 256
#define NL 255   // labels 0..254 (class 255 excluded)

typedef unsigned long long u64;
typedef unsigned int u32;
typedef unsigned short u16;
typedef unsigned char u8;

__device__ __forceinline__ u32 ord_f32(float f) {
  u32 b = __float_as_uint(f);
  return (b & 0x80000000u) ? ~b : (b | 0x80000000u);
}

// Kernel A: 16 lanes per query (4 queries per wave). PROVEN absmax=0 since r5 —
// arithmetic and reduction DAG must not change.
__global__ __launch_bounds__(256) void score_box_kernel(
    const float* __restrict__ logits,
    const float* __restrict__ pboxes,
    const int* __restrict__ tsz,
    float* __restrict__ out)
{
#pragma clang fp contract(off)
  const int lane = threadIdx.x & 63;
  const int g = lane & 15;            // sub-lane within the 16-lane group
  const int wv = threadIdx.x >> 6;
  const int q = (blockIdx.x * 4 + wv) * 4 + (lane >> 4);  // 16 queries/block
  const float* row = logits + (size_t)q * NC + g * 16;
  const float4 la = *reinterpret_cast<const float4*>(row);
  const float4 lb4 = *reinterpret_cast<const float4*>(row + 4);
  const float4 lc = *reinterpret_cast<const float4*>(row + 8);
  const float4 ld = *reinterpret_cast<const float4*>(row + 12);

  float m = fmaxf(fmaxf(fmaxf(la.x, la.y), fmaxf(la.z, la.w)),
           fmaxf(fmaxf(fmaxf(lb4.x, lb4.y), fmaxf(lb4.z, lb4.w)),
           fmaxf(fmaxf(fmaxf(lc.x, lc.y), fmaxf(lc.z, lc.w)),
                 fmaxf(fmaxf(ld.x, ld.y), fmaxf(ld.z, ld.w)))));
  #pragma unroll
  for (int d = 1; d < 16; d <<= 1) m = fmaxf(m, __shfl_xor(m, d));

  float4 ea, eb, ec, ed;
  ea.x = expf(la.x - m);  ea.y = expf(la.y - m);  ea.z = expf(la.z - m);  ea.w = expf(la.w - m);
  eb.x = expf(lb4.x - m); eb.y = expf(lb4.y - m); eb.z = expf(lb4.z - m); eb.w = expf(lb4.w - m);
  ec.x = expf(lc.x - m);  ec.y = expf(lc.y - m);  ec.z = expf(lc.z - m);  ec.w = expf(lc.w - m);
  ed.x = expf(ld.x - m);  ed.y = expf(ld.y - m);  ed.z = expf(ld.z - m);  ed.w = expf(ld.w - m);

  float s = (((ea.x + ea.y) + (ea.z + ea.w)) + ((eb.x + eb.y) + (eb.z + eb.w)))
          + (((ec.x + ec.y) + (ec.z + ec.w)) + ((ed.x + ed.y) + (ed.z + ed.w)));
  #pragma unroll
  for (int d = 1; d < 16; d <<= 1) s += __shfl_xor(s, d);

  const int c0 = g * 16;
  float bp = ea.x / s; int bc = c0;
  float p;
  p = ea.y / s; if (p > bp) { bp = p; bc = c0 + 1; }
  p = ea.z / s; if (p > bp) { bp = p; bc = c0 + 2; }
  p = ea.w / s; if (p > bp) { bp = p; bc = c0 + 3; }
  p = eb.x / s; if (p > bp) { bp = p; bc = c0 + 4; }
  p = eb.y / s; if (p > bp) { bp = p; bc = c0 + 5; }
  p = eb.z / s; if (p > bp) { bp = p; bc = c0 + 6; }
  p = eb.w / s; if (p > bp) { bp = p; bc = c0 + 7; }
  p = ec.x / s; if (p > bp) { bp = p; bc = c0 + 8; }
  p = ec.y / s; if (p > bp) { bp = p; bc = c0 + 9; }
  p = ec.z / s; if (p > bp) { bp = p; bc = c0 + 10; }
  p = ec.w / s; if (p > bp) { bp = p; bc = c0 + 11; }
  p = ed.x / s; if (p > bp) { bp = p; bc = c0 + 12; }
  p = ed.y / s; if (p > bp) { bp = p; bc = c0 + 13; }
  p = ed.z / s; if (p > bp) { bp = p; bc = c0 + 14; }
  p = ed.w / s; if (g != 15 && p > bp) { bp = p; bc = c0 + 15; }  // skip class 255
  #pragma unroll
  for (int d = 1; d < 16; d <<= 1) {
    const float op = __shfl_xor(bp, d);
    const int   oc = __shfl_xor(bc, d);
    if (op > bp || (op == bp && oc < bc)) { bp = op; bc = oc; }
  }

  if (g == 0) {
    const int b = q >> 11;
    float hf = (float)tsz[b * 2 + 0];
    float wf = (float)tsz[b * 2 + 1];
    float4 pb = *reinterpret_cast<const float4*>(pboxes + (size_t)q * 4);
    float hw = 0.5f * pb.z, hh = 0.5f * pb.w;
    float4 ob;
    ob.x = (pb.x - hw) * wf;
    ob.y = (pb.y - hh) * hf;
    ob.z = (pb.x + hw) * wf;
    ob.w = (pb.y + hh) * hf;
    *reinterpret_cast<float4*>(out + (size_t)q * 4) = ob;
    out[NB * BQ * 4 + q] = bp;
    out[NB * BQ * 5 + q] = (float)bc;
  }
}

// Kernel B: one 1024-thread block per batch.
// Compact valid keys -> TILED rank pass (64x64 work items over all 16 waves,
// wave-uniform broadcast reads, unrolled -> throughput-bound) -> ballot-match
// label grouping (r4-proven) -> bitmask NMS -> writeback.
__global__ __launch_bounds__(1024) void sort_nms_kernel(float* __restrict__ out)
{
#pragma clang fp contract(off)
  __shared__ __align__(16) u64 cvk[BQ];  // compact valid keys; REUSED as suppression masks after the sweep
  __shared__ u32 cgt_a[BQ];              // per-slot rank accumulators
  __shared__ float4 bx[BQ];              // boxes by orig idx
  __shared__ float4 bxo[BQ];             // label-offset coords by sorted position
  __shared__ float scr[BQ];              // raw scores by orig idx
  __shared__ u8 lb[BQ];                  // labels by orig idx
  __shared__ u8 lbp[BQ];                 // label by sorted position (255 = invalid)
  __shared__ u8 kp[BQ];                  // keep flags by sorted position
  __shared__ u16 sidx[BQ];               // orig idx by sorted position
  __shared__ u16 gpos[BQ];               // sorted position by group slot
  __shared__ u16 hist[32 * 256];         // [chunk][label] counts -> excl prefix
  __shared__ u32 tot[256];               // per-label totals
  __shared__ u32 scn[256];               // inclusive label-count scan
  __shared__ u32 wval[16], winv[16];     // per-wave valid/invalid counts

  const int b = blockIdx.x;
  const int tid = threadIdx.x;
  const int lane = tid & 63;
  const int wv = tid >> 6;
  float* boxes_g  = out + (size_t)b * BQ * 4;
  float* scores_g = out + NB * BQ * 4 + (size_t)b * BQ;
  float* labels_g = out + NB * BQ * 5 + (size_t)b * BQ;
  float* keep_g   = out + NB * BQ * 6 + (size_t)b * BQ;

  // ---- phase 1: load, stage, zero accumulators ----
  const int q0 = 2 * tid;
  float2 s2 = *reinterpret_cast<const float2*>(scores_g + q0);
  float2 lf = *reinterpret_cast<const float2*>(labels_g + q0);
  float4 bb0 = *reinterpret_cast<const float4*>(boxes_g + (size_t)q0 * 4);
  float4 bb1 = *reinterpret_cast<const float4*>(boxes_g + (size_t)q0 * 4 + 4);
  scr[q0] = s2.x; scr[q0 + 1] = s2.y;
  const u32 l0 = (u32)(int)lf.x, l1 = (u32)(int)lf.y;
  lb[q0] = (u8)l0; lb[q0 + 1] = (u8)l1;
  bx[q0] = bb0; bx[q0 + 1] = bb1;
  cgt_a[tid] = 0; cgt_a[tid + 1024] = 0;
  reinterpret_cast<u32*>(hist)[tid]        = 0;
  reinterpret_cast<u32*>(hist)[tid + 1024] = 0;
  reinterpret_cast<u32*>(hist)[tid + 2048] = 0;
  reinterpret_cast<u32*>(hist)[tid + 3072] = 0;
  const bool v0 = (s2.x >= 0.05f), v1 = (s2.y >= 0.05f);
  // key: (ord<<32)|(idx<<8)|label — label bits below idx never decide order
  const u64 f0 = ((u64)(v0 ? ord_f32(s2.x) : 0x007FFFFFu) << 32) | ((u32)q0 << 8) | l0;
  const u64 f1 = ((u64)(v1 ? ord_f32(s2.y) : 0x007FFFFFu) << 32) | ((u32)(q0 + 1) << 8) | l1;
  const u64 b0 = __ballot(v0), b1 = __ballot(v1);
  if (lane == 0) {
    const u32 c = (u32)(__popcll(b0) + __popcll(b1));
    wval[wv] = c;
    winv[wv] = 128u - c;
  }
  __syncthreads();  // B0

  int nv = 0, voff = 0, ioff = 0;
  #pragma unroll
  for (int w = 0; w < 16; ++w) {
    const int c = (int)wval[w];
    nv += c;
    if (w < wv) { voff += c; ioff += (int)winv[w]; }
  }
  const int tinv = BQ - nv;
  const u64 below = (1ull << lane) - 1ull;
  const int vr0 = voff + (int)__popcll(b0 & below) + (int)__popcll(b1 & below);
  const int ir0 = ioff + (int)__popcll(~b0 & below) + (int)__popcll(~b1 & below);
  const int vr1 = vr0 + (v0 ? 1 : 0);
  const int ir1 = ir0 + (v0 ? 0 : 1);
  // compact valid keys; invalid tail placed directly (descending orig idx —
  // exact reversed-stable semantics for the -inf block, proven r3-r6)
  if (v0) cvk[vr0] = f0;
  else { const int ip = nv + (tinv - 1 - ir0); sidx[ip] = (u16)q0; lbp[ip] = 255; kp[ip] = 0; }
  if (v1) cvk[vr1] = f1;
  else { const int ip = nv + (tinv - 1 - ir1); sidx[ip] = (u16)(q0 + 1); lbp[ip] = 255; kp[ip] = 0; }
  __syncthreads();  // B1

  // ---- phase 2: tiled rank pass ----
  // nvc^2 work items (64x64 tiles of the compare matrix) spread over 16 waves.
  // Within an item: lane owns slot sc*64+lane; the j-loop reads wave-uniform
  // addresses (LDS broadcast) with unroll-8 for pipelining.
  const int nvc = (nv + 63) >> 6;
  const int nitems = nvc * nvc;
  for (int it = wv; it < nitems; it += 16) {
    const int sc_ = it / nvc;
    const int jc = it - sc_ * nvc;
    const int slot = (sc_ << 6) + lane;
    const u64 ki = cvk[slot];          // slot < 2048 always; junk harmless
    const int j0 = jc << 6;
    int lim = nv - j0; if (lim > 64) lim = 64;
    const u64* jp = &cvk[j0];
    int cgt = 0;
    #pragma unroll 8
    for (int l = 0; l < lim; ++l) cgt += (jp[l] > ki) ? 1 : 0;
    if (slot < nv && cgt) atomicAdd(&cgt_a[slot], (u32)cgt);
  }
  __syncthreads();  // B2

  // ---- phase 3: sweep — place by rank, stage per-position label/idx/offset box ----
  for (int slot = tid; slot < nv; slot += 1024) {
    const u64 ki = cvk[slot];
    const u32 p = cgt_a[slot];          // sorted position (descending key)
    const u32 oi = (u32)(ki >> 8) & (BQ - 1);
    const u32 li = (u32)ki & 255u;
    sidx[p] = (u16)oi;
    lbp[p] = (u8)li;
    const float lc = (float)li * 100000.0f;
    const float4 A = bx[oi];
    float4 Ao;
    Ao.x = A.x + lc; Ao.y = A.y + lc; Ao.z = A.z + lc; Ao.w = A.w + lc;
    bxo[p] = Ao;
  }
  __syncthreads();  // B3

  // ---- phase 4: ballot-match label ranks per 64-position chunk (r4-proven) ----
  int lA, lB; u32 rA, rB;
  {
    const int p = tid;
    lA = (int)lbp[p];
    u64 m = ~0ull;
    #pragma unroll
    for (int bt = 0; bt < 8; ++bt) {
      const u64 vb = __ballot(((lA >> bt) & 1));
      m &= ((lA >> bt) & 1) ? vb : ~vb;
    }
    rA = (u32)__popcll(m & below);
    if (lane == 63 - __builtin_clzll(m)) hist[(p >> 6) * 256 + lA] = (u16)__popcll(m);
  }
  {
    const int p = tid + 1024;
    lB = (int)lbp[p];
    u64 m = ~0ull;
    #pragma unroll
    for (int bt = 0; bt < 8; ++bt) {
      const u64 vb = __ballot(((lB >> bt) & 1));
      m &= ((lB >> bt) & 1) ? vb : ~vb;
    }
    rB = (u32)__popcll(m & below);
    if (lane == 63 - __builtin_clzll(m)) hist[(p >> 6) * 256 + lB] = (u16)__popcll(m);
  }
  __syncthreads();  // B4

  // ---- phase 5: per-label exclusive prefix over chunks ----
  if (tid < 256) {
    u32 run = 0;
    #pragma unroll
    for (int c = 0; c < 32; ++c) {
      const u32 v = hist[c * 256 + tid];
      hist[c * 256 + tid] = (u16)run;
      run += v;
    }
    tot[tid] = run;
  }
  __syncthreads();  // B5

  // ---- phase 6: inclusive label-offset scan by wave 0 ----
  if (tid < 64) {
    u32 carry = 0;
    for (int seg = 0; seg < 4; ++seg) {
      const int l = seg * 64 + tid;
      u32 x = tot[l];
      #pragma unroll
      for (int s = 1; s < 64; s <<= 1) {
        const u32 y = __shfl_up(x, s, 64);
        if (lane >= s) x += y;
      }
      scn[l] = x + carry;
      carry += __shfl(x, 63, 64);
    }
  }
  __syncthreads();  // B6

  // ---- phase 7: scatter group slots (ascending sorted position per label) ----
  u32 gA, gB;
  {
    const int p = tid;
    const u32 st = (lA == 0) ? 0u : scn[lA - 1];
    gA = (u32)hist[(p >> 6) * 256 + lA] + rA;
    gpos[st + gA] = (u16)p;
  }
  {
    const int p = tid + 1024;
    const u32 st = (lB == 0) ? 0u : scn[lB - 1];
    gB = (u32)hist[(p >> 6) * 256 + lB] + rB;
    gpos[st + gB] = (u16)p;
  }
  __syncthreads();  // B7

  // ---- phase 8: overlap bitmasks vs earlier same-label members ----
  // (cvk is dead as keys now — reuse it as the mask array)
  #pragma unroll
  for (int half = 0; half < 2; ++half) {
    const int p = tid + half * 1024;
    const int l = half ? lB : lA;
    const u32 g = half ? gB : gA;
    if (p < nv && g < 64) {
      const u32 st = (l == 0) ? 0u : scn[l - 1];
      const float4 Ao = bxo[p];
      const float areaA = fmaxf(Ao.z - Ao.x, 0.0f) * fmaxf(Ao.w - Ao.y, 0.0f);
      u64 m = 0;
      for (u32 r = 0; r < g; ++r) {
        const int p2 = gpos[st + r];
        const float4 Bo = bxo[p2];
        const float areaB = fmaxf(Bo.z - Bo.x, 0.0f) * fmaxf(Bo.w - Bo.y, 0.0f);
        const float ltx = fmaxf(Ao.x, Bo.x), lty = fmaxf(Ao.y, Bo.y);
        const float rbx = fminf(Ao.z, Bo.z), rby = fminf(Ao.w, Bo.w);
        const float iw = fmaxf(rbx - ltx, 0.0f), ih = fmaxf(rby - lty, 0.0f);
        const float inter = iw * ih;
        const float uni = (areaA + areaB) - inter;
        const float iou = inter / fmaxf(uni, 1e-6f);
        if (iou > 0.7f) m |= (1ull << r);
      }
      cvk[st + g] = m;
    }
  }
  __syncthreads();  // B8

  // ---- phase 9: per-label greedy resolution (bitops; serial fallback k>64) ----
  if (tid < NL) {
    const int k = (int)tot[tid];
    if (k > 0) {
      const int st = (tid == 0) ? 0 : (int)scn[tid - 1];
      if (k <= 64) {
        u64 kept = 0;
        for (int r = 0; r < k; ++r) {
          const u64 m = cvk[st + r];
          const int keep = ((m & kept) == 0) ? 1 : 0;
          kept |= (u64)keep << r;
          kp[gpos[st + r]] = (u8)keep;
        }
      } else {
        for (int a = 0; a < k; ++a) {
          const int p = gpos[st + a];
          const float4 Ao = bxo[p];
          const float areaA = fmaxf(Ao.z - Ao.x, 0.0f) * fmaxf(Ao.w - Ao.y, 0.0f);
          int keep = 1;
          for (int e = 0; e < a; ++e) {
            const int p2 = gpos[st + e];
            if (!kp[p2]) continue;
            const float4 Bo = bxo[p2];
            const float areaB = fmaxf(Bo.z - Bo.x, 0.0f) * fmaxf(Bo.w - Bo.y, 0.0f);
            const float ltx = fmaxf(Ao.x, Bo.x), lty = fmaxf(Ao.y, Bo.y);
            const float rbx = fminf(Ao.z, Bo.z), rby = fminf(Ao.w, Bo.w);
            const float iw = fmaxf(rbx - ltx, 0.0f), ih = fmaxf(rby - lty, 0.0f);
            const float inter = iw * ih;
            const float uni = (areaA + areaB) - inter;
            const float iou = inter / fmaxf(uni, 1e-6f);
            if (iou > 0.7f) { keep = 0; break; }
          }
          kp[p] = (u8)keep;
        }
      }
    }
  }
  __syncthreads();  // B9

  // ---- phase 10: writeback sorted outputs ----
  {
    const int p = tid;
    const u32 oi = sidx[p];
    *reinterpret_cast<float4*>(boxes_g + (size_t)p * 4) = bx[oi];
    scores_g[p] = scr[oi];
    labels_g[p] = (float)lb[oi];
    keep_g[p]   = kp[p] ? 1.0f : 0.0f;
  }
  {
    const int p = tid + 1024;
    const u32 oi = sidx[p];
    *reinterpret_cast<float4*>(boxes_g + (size_t)p * 4) = bx[oi];
    scores_g[p] = scr[oi];
    labels_g[p] = (float)lb[oi];
    keep_g[p]   = kp[p] ? 1.0f : 0.0f;
  }
}

extern "C" void kernel_launch(void* const* d_in, const int* in_sizes, int n_in,
                              void* d_out, int out_size, void* d_ws, size_t ws_size,
                              hipStream_t stream) {
  const float* logits = (const float*)d_in[0];
  const float* pboxes = (const float*)d_in[1];
  const int*   tsz    = (const int*)d_in[2];
  float* out = (float*)d_out;
  score_box_kernel<<<NB * BQ / 16, 256, 0, stream>>>(logits, pboxes, tsz, out);
  sort_nms_kernel<<<NB, 1024, 0, stream>>>(out);
}